// Round 2
// baseline (631.349 us; speedup 1.0000x reference)
//
#include <hip/hip_runtime.h>

// ConvAttention: B=8, C=64, H=W=256, 3x3, fp32.
// v3 = v1's register data path x v2's occupancy.
// Block (256 thr = 4 waves) = one image row. Each wave handles 16 of the
// 64 channels with the v1 scheme: lane owns 4 cols (float4), taps come
// from registers via __shfl (zero redundant loads, all 16B-aligned).
// Partial scores s[4][9] are summed across the 4 waves through a 9KB LDS
// buffer (4 chunks of [256][9] f32; stride-9 => 2-way banks = free).
// Softmax weights are shared by all channels, so pass 2 splits channels
// across waves with no further communication.
// Grid (256,8) = 2048 blocks = 32 waves/CU; XCD swizzle keeps an image's
// rows on one XCD so the +/-1-row k/v re-reads hit its private L2.

constexpr int B = 8, C = 64, H = 256, W = 256;
constexpr int CPW = C / 4;  // channels per wave

__global__ __launch_bounds__(256, 8) void conv_attn_kernel(
    const float* __restrict__ qg, const float* __restrict__ kg,
    const float* __restrict__ vg, float* __restrict__ og) {
  const int lin = blockIdx.y * (int)gridDim.x + blockIdx.x;   // 0..2047
  const int swz = (lin & 7) * ((H * B) / 8) + (lin >> 3);     // bijective
  const int y    = swz & (H - 1);
  const int b    = swz >> 8;
  const int lane = threadIdx.x & 63;
  const int wv   = threadIdx.x >> 6;
  const int c0   = wv * CPW;

  const size_t cs    = (size_t)H * W;
  const size_t ibase = (size_t)b * C * cs + (size_t)y * W + lane * 4;
  const bool up_ok = (y > 0), dn_ok = (y < H - 1);
  const float4 z4 = make_float4(0.f, 0.f, 0.f, 0.f);

  float s[4][9];
#pragma unroll
  for (int j = 0; j < 4; ++j)
#pragma unroll
    for (int t = 0; t < 9; ++t) s[j][t] = 0.f;

  // ---------------- pass 1: partial scores over this wave's channels ----
#pragma unroll 2
  for (int ci = 0; ci < CPW; ++ci) {
    const size_t cb = ibase + (size_t)(c0 + ci) * cs;
    float4 qv = *(const float4*)(qg + cb);
    float qa[4] = {qv.x, qv.y, qv.z, qv.w};
    const float* kp = kg + cb;
    float4 kr[3];
    kr[0] = up_ok ? *(const float4*)(kp - W) : z4;
    kr[1] = *(const float4*)kp;
    kr[2] = dn_ok ? *(const float4*)(kp + W) : z4;
#pragma unroll
    for (int dy = 0; dy < 3; ++dy) {
      float lf = __shfl_up(kr[dy].w, 1u);
      if (lane == 0) lf = 0.f;
      float rt = __shfl_down(kr[dy].x, 1u);
      if (lane == 63) rt = 0.f;
      float col[6] = {lf, kr[dy].x, kr[dy].y, kr[dy].z, kr[dy].w, rt};
#pragma unroll
      for (int j = 0; j < 4; ++j)
#pragma unroll
        for (int dx = 0; dx < 3; ++dx)
          s[j][dy * 3 + dx] = fmaf(qa[j], col[j + dx], s[j][dy * 3 + dx]);
    }
  }

  // ---------------- cross-wave reduction of s (4 chunks of 9KB LDS) ----
  __shared__ float red[256][9];
#pragma unroll
  for (int j = 0; j < 4; ++j) {
    if (j) __syncthreads();   // prior chunk's reads done before overwrite
#pragma unroll
    for (int t = 0; t < 9; ++t) red[threadIdx.x][t] = s[j][t];
    __syncthreads();
    float tot[9];
#pragma unroll
    for (int t = 0; t < 9; ++t) tot[t] = 0.f;
#pragma unroll
    for (int w2 = 0; w2 < 4; ++w2)
#pragma unroll
      for (int t = 0; t < 9; ++t) tot[t] += red[w2 * 64 + lane][t];
#pragma unroll
    for (int t = 0; t < 9; ++t) s[j][t] = tot[t];
  }

  // ---------------- softmax over 9 taps ----------------
#pragma unroll
  for (int j = 0; j < 4; ++j) {
    float m = s[j][0];
#pragma unroll
    for (int t = 1; t < 9; ++t) m = fmaxf(m, s[j][t]);
    float sum = 0.f;
#pragma unroll
    for (int t = 0; t < 9; ++t) { s[j][t] = __expf(s[j][t] - m); sum += s[j][t]; }
    float inv = 1.f / sum;
#pragma unroll
    for (int t = 0; t < 9; ++t) s[j][t] *= inv;
  }

  // ---------------- pass 2: weighted v sum over this wave's channels ---
#pragma unroll 2
  for (int ci = 0; ci < CPW; ++ci) {
    const size_t cb = ibase + (size_t)(c0 + ci) * cs;
    const float* vp = vg + cb;
    float4 vr[3];
    vr[0] = up_ok ? *(const float4*)(vp - W) : z4;
    vr[1] = *(const float4*)vp;
    vr[2] = dn_ok ? *(const float4*)(vp + W) : z4;
    float o[4] = {0.f, 0.f, 0.f, 0.f};
#pragma unroll
    for (int dy = 0; dy < 3; ++dy) {
      float lf = __shfl_up(vr[dy].w, 1u);
      if (lane == 0) lf = 0.f;
      float rt = __shfl_down(vr[dy].x, 1u);
      if (lane == 63) rt = 0.f;
      float col[6] = {lf, vr[dy].x, vr[dy].y, vr[dy].z, vr[dy].w, rt};
#pragma unroll
      for (int j = 0; j < 4; ++j)
#pragma unroll
        for (int dx = 0; dx < 3; ++dx)
          o[j] = fmaf(s[j][dy * 3 + dx], col[j + dx], o[j]);
    }
    *(float4*)(og + cb) = make_float4(o[0], o[1], o[2], o[3]);
  }
}

extern "C" void kernel_launch(void* const* d_in, const int* in_sizes, int n_in,
                              void* d_out, int out_size, void* d_ws, size_t ws_size,
                              hipStream_t stream) {
  const float* q = (const float*)d_in[0];
  const float* k = (const float*)d_in[1];
  const float* v = (const float*)d_in[2];
  float* out = (float*)d_out;
  dim3 grid(H, B);
  conv_attn_kernel<<<grid, dim3(256), 0, stream>>>(q, k, v, out);
}

// Round 3
// 426.589 us; speedup vs baseline: 1.4800x; 1.4800x over previous
//
#include <hip/hip_runtime.h>

// ConvAttention: B=8, C=64, H=W=256, 3x3, fp32.
// v4 = v3 un-spilled. v3's launch_bounds(256,8) capped VGPR at 64; the
// ~65 live registers of pass 1 spilled to scratch (WRITE_SIZE 634 MB vs
// 131 MB output). Fix: launch_bounds(256,4) -> 128 VGPR, 4 waves/SIMD
// (50% occupancy) -- still 2x v1's latency hiding, with v1's
// zero-redundancy float4+shfl data path intact.
// Structure: block (4 waves) = one image row; each wave does 16 of 64
// channels; partial scores s[4][9] reduced across waves via one 36 KB
// LDS buffer (stride-9 rows => 2-way banks = free); softmax once;
// pass 2 splits channels across waves, no further communication.
// Grid (256,8) = 2048 blocks; XCD swizzle keeps an image's rows on one
// XCD so +/-1-row k/v re-reads hit its private L2.

constexpr int B = 8, C = 64, H = 256, W = 256;
constexpr int CPW = C / 4;  // channels per wave

__global__ __launch_bounds__(256, 4) void conv_attn_kernel(
    const float* __restrict__ qg, const float* __restrict__ kg,
    const float* __restrict__ vg, float* __restrict__ og) {
  const int lin = blockIdx.y * (int)gridDim.x + blockIdx.x;   // 0..2047
  const int swz = (lin & 7) * ((H * B) / 8) + (lin >> 3);     // bijective
  const int y    = swz & (H - 1);
  const int b    = swz >> 8;
  const int lane = threadIdx.x & 63;
  const int wv   = threadIdx.x >> 6;
  const int c0   = wv * CPW;

  const size_t cs    = (size_t)H * W;
  const size_t ibase = (size_t)b * C * cs + (size_t)y * W + lane * 4;
  const bool up_ok = (y > 0), dn_ok = (y < H - 1);
  const float4 z4 = make_float4(0.f, 0.f, 0.f, 0.f);

  float s[4][9];
#pragma unroll
  for (int j = 0; j < 4; ++j)
#pragma unroll
    for (int t = 0; t < 9; ++t) s[j][t] = 0.f;

  // ---------------- pass 1: partial scores over this wave's channels ----
#pragma unroll 2
  for (int ci = 0; ci < CPW; ++ci) {
    const size_t cb = ibase + (size_t)(c0 + ci) * cs;
    float4 qv = *(const float4*)(qg + cb);
    float qa[4] = {qv.x, qv.y, qv.z, qv.w};
    const float* kp = kg + cb;
    float4 kr[3];
    kr[0] = up_ok ? *(const float4*)(kp - W) : z4;
    kr[1] = *(const float4*)kp;
    kr[2] = dn_ok ? *(const float4*)(kp + W) : z4;
#pragma unroll
    for (int dy = 0; dy < 3; ++dy) {
      float lf = __shfl_up(kr[dy].w, 1u);
      if (lane == 0) lf = 0.f;
      float rt = __shfl_down(kr[dy].x, 1u);
      if (lane == 63) rt = 0.f;
      float col[6] = {lf, kr[dy].x, kr[dy].y, kr[dy].z, kr[dy].w, rt};
#pragma unroll
      for (int j = 0; j < 4; ++j)
#pragma unroll
        for (int dx = 0; dx < 3; ++dx)
          s[j][dy * 3 + dx] = fmaf(qa[j], col[j + dx], s[j][dy * 3 + dx]);
    }
  }

  // ---------------- cross-wave reduction of s (36 KB LDS, one sync) ----
  __shared__ float red[4][256][9];
#pragma unroll
  for (int j = 0; j < 4; ++j)
#pragma unroll
    for (int t = 0; t < 9; ++t) red[j][threadIdx.x][t] = s[j][t];
  __syncthreads();
#pragma unroll
  for (int j = 0; j < 4; ++j) {
    float tot[9];
#pragma unroll
    for (int t = 0; t < 9; ++t) tot[t] = 0.f;
#pragma unroll
    for (int w2 = 0; w2 < 4; ++w2)
#pragma unroll
      for (int t = 0; t < 9; ++t) tot[t] += red[j][w2 * 64 + lane][t];
#pragma unroll
    for (int t = 0; t < 9; ++t) s[j][t] = tot[t];
  }

  // ---------------- softmax over 9 taps ----------------
#pragma unroll
  for (int j = 0; j < 4; ++j) {
    float m = s[j][0];
#pragma unroll
    for (int t = 1; t < 9; ++t) m = fmaxf(m, s[j][t]);
    float sum = 0.f;
#pragma unroll
    for (int t = 0; t < 9; ++t) { s[j][t] = __expf(s[j][t] - m); sum += s[j][t]; }
    float inv = 1.f / sum;
#pragma unroll
    for (int t = 0; t < 9; ++t) s[j][t] *= inv;
  }

  // ---------------- pass 2: weighted v sum over this wave's channels ---
#pragma unroll 2
  for (int ci = 0; ci < CPW; ++ci) {
    const size_t cb = ibase + (size_t)(c0 + ci) * cs;
    const float* vp = vg + cb;
    float4 vr[3];
    vr[0] = up_ok ? *(const float4*)(vp - W) : z4;
    vr[1] = *(const float4*)vp;
    vr[2] = dn_ok ? *(const float4*)(vp + W) : z4;
    float o[4] = {0.f, 0.f, 0.f, 0.f};
#pragma unroll
    for (int dy = 0; dy < 3; ++dy) {
      float lf = __shfl_up(vr[dy].w, 1u);
      if (lane == 0) lf = 0.f;
      float rt = __shfl_down(vr[dy].x, 1u);
      if (lane == 63) rt = 0.f;
      float col[6] = {lf, vr[dy].x, vr[dy].y, vr[dy].z, vr[dy].w, rt};
#pragma unroll
      for (int j = 0; j < 4; ++j)
#pragma unroll
        for (int dx = 0; dx < 3; ++dx)
          o[j] = fmaf(s[j][dy * 3 + dx], col[j + dx], o[j]);
    }
    *(float4*)(og + cb) = make_float4(o[0], o[1], o[2], o[3]);
  }
}

extern "C" void kernel_launch(void* const* d_in, const int* in_sizes, int n_in,
                              void* d_out, int out_size, void* d_ws, size_t ws_size,
                              hipStream_t stream) {
  const float* q = (const float*)d_in[0];
  const float* k = (const float*)d_in[1];
  const float* v = (const float*)d_in[2];
  float* out = (float*)d_out;
  dim3 grid(H, B);
  conv_attn_kernel<<<grid, dim3(256), 0, stream>>>(q, k, v, out);
}